// Round 8
// baseline (1142.269 us; speedup 1.0000x reference)
//
#include <hip/hip_runtime.h>

typedef __attribute__((ext_vector_type(8))) short s16x8;
typedef __attribute__((ext_vector_type(4))) float f32x4;
typedef __attribute__((ext_vector_type(2))) float f32x2;

// ---------------- bf16 helpers (RNE) ----------------
__device__ __forceinline__ unsigned short f2bf(float x) {
  unsigned u = __float_as_uint(x);
  u = (u + 0x7fffu + ((u >> 16) & 1u)) >> 16;
  return (unsigned short)u;
}
__device__ __forceinline__ unsigned cvt_pk_bf16(float a, float b) {
  unsigned r;
  asm("v_cvt_pk_bf16_f32 %0, %1, %2" : "=v"(r) : "v"(a), "v"(b));
  return r;
}
__device__ __forceinline__ float bflo(unsigned v) { return __uint_as_float(v << 16); }
__device__ __forceinline__ float bfhi(unsigned v) { return __uint_as_float(v & 0xffff0000u); }

// lgkm-only barrier: orders LDS across the block WITHOUT draining vmcnt --
// in-flight global B prefetches survive across it.
__device__ __forceinline__ void lgkm_barrier() {
  asm volatile("s_waitcnt lgkmcnt(0)" ::: "memory");
  __builtin_amdgcn_s_barrier();
  asm volatile("" ::: "memory");
}

// ---------------- ws layout (ushort units) ----------------
#define FEAT_OFF 0
#define W0F_OFF  2097152
#define W1F_OFF  (W0F_OFF + 24576)
#define W2F_OFF  (W1F_OFF + 65536)
#define W3P_OFF  (W2F_OFF + 65536)
#define WS_TOTAL (W3P_OFF + 512)

// H columns are stored permuted: position k' holds logical col
//   col_log(k') = (k'&0xC0) | ((k'&3)<<4) | ((k'>>2)&15)
__device__ __forceinline__ int col_log(int kp) {
  return (kp & 0xC0) | ((kp & 3) << 4) | ((kp >> 2) & 15);
}
// LDS h tile: 64x256 bf16, XOR-swizzled (T2) in place of padding:
//   idx(row,col) = row*256 + (col ^ ((row&7)<<3))
// bijective, preserves 16B/8B alignment (xor operand multiple of 8 shorts).
// Correctness + conflict-neutrality validated in r7.
__device__ __forceinline__ int hswz(int row, int col) {
  return row * 256 + (col ^ ((row & 7) << 3));
}

__global__ void liif_prep(const float* __restrict__ inp,
                          const float* __restrict__ W0,
                          const float* __restrict__ W1,
                          const float* __restrict__ W2,
                          const float* __restrict__ W3,
                          unsigned short* __restrict__ ws) {
  int tid = blockIdx.x * 256 + threadIdx.x;
  if (tid < 2097152) {
    int pos = tid >> 6, c = tid & 63;
    ws[FEAT_OFF + tid] = f2bf(inp[c * 32768 + pos]);
  } else if (tid < W1F_OFF) {
    int e = tid - W0F_OFF;
    int j = e & 7, L = (e >> 3) & 63, nt = (e >> 9) & 15, c = e >> 13;
    int k = c * 32 + (L >> 4) * 8 + j, n = nt * 16 + (L & 15);
    ws[tid] = (k < 71) ? f2bf(W0[k * 256 + n]) : (unsigned short)0;
  } else if (tid < W2F_OFF) {
    int e = tid - W1F_OFF;
    int j = e & 7, L = (e >> 3) & 63, nt = (e >> 9) & 15, c = e >> 13;
    int kp = c * 32 + (L >> 4) * 8 + j, n = nt * 16 + (L & 15);
    ws[tid] = f2bf(W1[col_log(kp) * 256 + n]);
  } else if (tid < W3P_OFF) {
    int e = tid - W2F_OFF;
    int j = e & 7, L = (e >> 3) & 63, nt = (e >> 9) & 15, c = e >> 13;
    int kp = c * 32 + (L >> 4) * 8 + j, n = nt * 16 + (L & 15);
    ws[tid] = f2bf(W2[col_log(kp) * 256 + n]);
  } else if (tid < W3P_OFF + 256) {
    int e = tid - W3P_OFF;
    float* w3p = (float*)(ws + W3P_OFF);
    w3p[e] = W3[col_log(e)];
  }
}

// One GEMM layer: 64 rows x 256 cols, 4 waves (wave = col-group).
// A: layer0 reads x at stride 104 (unswizzled); layers 1/2 read h via hswz.
// Bias folded into acc init. Epilogue: relu+cvt_pk+b64 swizzled stores.
// nb[] holds this layer's c=0 B-frags on entry; if PRE, exits with next
// layer's c=0 frags in flight (lgkm-only barriers keep vmcnt live).
template<int KC, bool PRE, bool SWZ>
__device__ __forceinline__ void run_layer(const unsigned short* __restrict__ Wf,
                                          const float* __restrict__ bias,
                                          const unsigned short* A,
                                          unsigned short* H,
                                          const unsigned short* __restrict__ Wnext,
                                          s16x8 (&nb)[4],
                                          int wave, int quad, int l16, int lane) {
  f32x4 acc[4][4];
#pragma unroll
  for (int ntl = 0; ntl < 4; ++ntl) {
    float bv = bias[(wave * 4 + ntl) * 16 + l16];
    f32x4 ai = (f32x4){bv, bv, bv, bv};
#pragma unroll
    for (int rt = 0; rt < 4; ++rt) acc[rt][ntl] = ai;
  }

  __builtin_amdgcn_s_setprio(1);
#pragma unroll
  for (int c = 0; c < KC; ++c) {
    s16x8 a[4];
#pragma unroll
    for (int rt = 0; rt < 4; ++rt) {
      int row = rt * 16 + l16, col = c * 32 + quad * 8;
      int idx = SWZ ? hswz(row, col) : row * 104 + col;
      a[rt] = *(const s16x8*)(A + idx);
    }
#pragma unroll
    for (int ntl = 0; ntl < 4; ++ntl) {
      int nt = wave * 4 + ntl;
      s16x8 b = (c == 0) ? nb[ntl]
                         : *(const s16x8*)(Wf + (((c * 16 + nt) * 64 + lane) << 3));
#pragma unroll
      for (int rt = 0; rt < 4; ++rt)
        acc[rt][ntl] = __builtin_amdgcn_mfma_f32_16x16x32_bf16(a[rt], b, acc[rt][ntl], 0, 0, 0);
    }
  }
  __builtin_amdgcn_s_setprio(0);

  if constexpr (PRE) {
#pragma unroll
    for (int ntl = 0; ntl < 4; ++ntl)
      nb[ntl] = *(const s16x8*)(Wnext + (((wave * 4 + ntl) * 64 + lane) << 3));
  }

  lgkm_barrier();  // all waves done reading A (aliases H); vmcnt stays live

  const int cb = wave * 64 + l16 * 4;  // col' base: 4 ntl-values contiguous
#pragma unroll
  for (int rt = 0; rt < 4; ++rt) {
#pragma unroll
    for (int i = 0; i < 4; ++i) {
      float v0 = fmaxf(acc[rt][0][i], 0.0f);
      float v1 = fmaxf(acc[rt][1][i], 0.0f);
      float v2 = fmaxf(acc[rt][2][i], 0.0f);
      float v3 = fmaxf(acc[rt][3][i], 0.0f);
      int r = rt * 16 + quad * 4 + i;
      uint2 pw = make_uint2(cvt_pk_bf16(v0, v1), cvt_pk_bf16(v2, v3));
      *(uint2*)(H + hswz(r, cb)) = pw;
    }
  }
  lgkm_barrier();  // H visible to all waves; prefetched vmcnt still live
}

// 256 threads, 64 rows (8 queries)/block. LDS = 64x256 bf16 = 32768 B EXACTLY
// -> 5 blocks/CU (160KB exact fit), 20 waves/CU (was 16). area/pred via
// shuffles (no LDS arrays). __launch_bounds__(256,5): 409-reg cap, no pressure.
__global__ __launch_bounds__(256, 5)
void liif_main(const float* __restrict__ coord,
               const float* __restrict__ cell,
               const float* __restrict__ b0,
               const float* __restrict__ b1,
               const float* __restrict__ b2,
               const float* __restrict__ b3,
               const unsigned short* __restrict__ ws,
               float* __restrict__ out) {
  __shared__ __align__(16) unsigned short sm_h[64 * 256];  // 32768 B
  unsigned short* sm_x = sm_h;  // x[64][104] aliases the front during sampling/L0

  const unsigned short* feat = ws + FEAT_OFF;
  const float* W3p = (const float*)(ws + W3P_OFF);
  const int tid = threadIdx.x;
  const int lane = tid & 63;
  const int wave = tid >> 6;
  const int quad = lane >> 4;
  const int l16 = lane & 15;
  const int qb = blockIdx.x * 8;

  // layer0 c=0 B prefetch: in flight across the whole sampling phase
  s16x8 nb[4];
#pragma unroll
  for (int ntl = 0; ntl < 4; ++ntl)
    nb[ntl] = *(const s16x8*)(ws + W0F_OFF + (((wave * 4 + ntl) * 64 + lane) << 3));

  float area = 0.0f;  // held in registers; combined via shuffles at the end

  // ---------------- sampling: 4 threads per row, 16 channels each ----------------
  {
    const int row = tid >> 2, p = tid & 3;
    const int ql = row >> 3, s = row & 7;
    const int q = qb + ql;
    const float c0r = coord[q * 3 + 0], c1r = coord[q * 3 + 1], c2r = coord[q * 3 + 2];
    const float R = 0.03125f;  // rx=ry=rz = 1/32
    const float sh0 = ((s & 4) ? R : -R) + 1e-6f;
    const float sh1 = ((s & 2) ? R : -R) + 1e-6f;
    const float sh2 = ((s & 1) ? R : -R) + 1e-6f;
    const float LO = -1.0f + 1e-6f, HI = 1.0f - 1e-6f;
    float c0 = fminf(fmaxf(c0r + sh0, LO), HI);
    float c1 = fminf(fmaxf(c1r + sh1, LO), HI);
    float c2 = fminf(fmaxf(c2r + sh2, LO), HI);
    float z = (c0 + 1.0f) * 16.0f - 0.5f;
    float y = (c1 + 1.0f) * 16.0f - 0.5f;
    float x = (c2 + 1.0f) * 16.0f - 0.5f;
    float zf = floorf(z), yf = floorf(y), xf = floorf(x);
    float wz = z - zf, wy = y - yf, wx = x - xf;
    int z0 = min(max((int)zf, 0), 31), z1 = min(max((int)zf + 1, 0), 31);
    int y0 = min(max((int)yf, 0), 31), y1 = min(max((int)yf + 1, 0), 31);
    int x0 = min(max((int)xf, 0), 31), x1 = min(max((int)xf + 1, 0), 31);
    float wz0 = 1.0f - wz, wy0 = 1.0f - wy, wx0 = 1.0f - wx;

    float w[8] = { wz0 * wy0 * wx0, wz0 * wy0 * wx, wz0 * wy * wx0, wz0 * wy * wx,
                   wz  * wy0 * wx0, wz  * wy0 * wx, wz  * wy * wx0, wz  * wy * wx };
    int idx[8] = { (z0 * 32 + y0) * 32 + x0, (z0 * 32 + y0) * 32 + x1,
                   (z0 * 32 + y1) * 32 + x0, (z0 * 32 + y1) * 32 + x1,
                   (z1 * 32 + y0) * 32 + x0, (z1 * 32 + y0) * 32 + x1,
                   (z1 * 32 + y1) * 32 + x0, (z1 * 32 + y1) * 32 + x1 };

    // packed f32x2 accumulation -> v_pk_fma_f32 (halves sampling FMA count)
    f32x2 acc2[8];
#pragma unroll
    for (int i = 0; i < 8; ++i) acc2[i] = (f32x2){0.f, 0.f};
#pragma unroll
    for (int corner = 0; corner < 8; ++corner) {
      const uint4* cp = (const uint4*)(feat + idx[corner] * 64 + p * 16);
      uint4 v0 = cp[0], v1 = cp[1];
      float wc = w[corner];
      f32x2 wc2 = (f32x2){wc, wc};
      unsigned vv[8] = { v0.x, v0.y, v0.z, v0.w, v1.x, v1.y, v1.z, v1.w };
#pragma unroll
      for (int d = 0; d < 8; ++d) {
        f32x2 xv = (f32x2){bflo(vv[d]), bfhi(vv[d])};
        acc2[d] += wc2 * xv;
      }
    }
    unsigned pw[8];
#pragma unroll
    for (int d = 0; d < 8; ++d)
      pw[d] = cvt_pk_bf16(acc2[d].x, acc2[d].y);
    uint4* dst = (uint4*)(&sm_x[row * 104 + p * 16]);
    dst[0] = make_uint4(pw[0], pw[1], pw[2], pw[3]);
    dst[1] = make_uint4(pw[4], pw[5], pw[6], pw[7]);

    if (p == 0) {
      const float step = 2.0f / 31.0f;
      float qc0 = wx0 * (-1.0f + step * x0) + wx * (-1.0f + step * x1);
      float qc1 = wy0 * (-1.0f + step * y0) + wy * (-1.0f + step * y1);
      float qc2 = wz0 * (-1.0f + step * z0) + wz * (-1.0f + step * z1);
      float rel0 = (c0r - qc0) * 32.0f;
      float rel1 = (c1r - qc1) * 32.0f;
      float rel2 = (c2r - qc2) * 32.0f;
      area = fabsf(rel0 * rel1 * rel2) + 1e-9f;
      float cl0 = cell[q * 3 + 0], cl1 = cell[q * 3 + 1], cl2 = cell[q * 3 + 2];
      float ssq = fminf(fmaxf(8.0f / (fabsf(cl0 * cl1 * cl2) + 1e-8f), 1.0f), 64.0f);
      unsigned tw0 = cvt_pk_bf16(rel0, rel1);
      unsigned tw1 = cvt_pk_bf16(rel2, cl0 * 32.0f);
      unsigned tw2 = cvt_pk_bf16(cl1 * 32.0f, cl2 * 32.0f);
      unsigned tw3 = cvt_pk_bf16(ssq, 0.0f);  // element 71 zero-padded
      uint4* d2 = (uint4*)(&sm_x[row * 104 + 64]);
      d2[0] = make_uint4(tw0, tw1, tw2, tw3);
      d2[1] = make_uint4(0, 0, 0, 0);  // cols 72..95 must be ZERO (K pad)
      d2[2] = make_uint4(0, 0, 0, 0);
      d2[3] = make_uint4(0, 0, 0, 0);
    }
  }
  lgkm_barrier();  // sampling writes visible; nb prefetch stays in flight

  // ---------------- MLP layers (bf16 MFMA, fp32 accum) ----------------
  run_layer<3, true,  false>(ws + W0F_OFF, b0, sm_x, sm_h, ws + W1F_OFF, nb, wave, quad, l16, lane);
  run_layer<8, true,  true >(ws + W1F_OFF, b1, sm_h, sm_h, ws + W2F_OFF, nb, wave, quad, l16, lane);
  run_layer<8, false, true >(ws + W2F_OFF, b2, sm_h, sm_h, nullptr,      nb, wave, quad, l16, lane);

  // ------- layer 3 (256->1) + area-weighted combine, all in registers -------
  {
    const int row = tid >> 2, p = tid & 3;
    float sum = 0.0f;
#pragma unroll
    for (int kk = 0; kk < 8; ++kk) {
      int col = p * 64 + kk * 8;
      const uint4 v = *(const uint4*)(sm_h + hswz(row, col));
      const float4 wa = *(const float4*)(W3p + col);
      const float4 wb = *(const float4*)(W3p + col + 4);
      sum += wa.x * bflo(v.x) + wa.y * bfhi(v.x);
      sum += wa.z * bflo(v.y) + wa.w * bfhi(v.y);
      sum += wb.x * bflo(v.z) + wb.y * bfhi(v.z);
      sum += wb.z * bflo(v.w) + wb.w * bfhi(v.w);
    }
    sum += __shfl_xor(sum, 1);
    sum += __shfl_xor(sum, 2);
    float pred = sum + b3[0];
    // this wave covers rows 16w..16w+15 = queries 2w, 2w+1; shift s of the
    // query at lane-half 'base' lives at lane base+4s (its p==0 thread).
    const int base = lane & 32;
    float tot = 0.0f, ret = 0.0f;
#pragma unroll
    for (int s = 0; s < 8; ++s) {
      float as = __shfl(area, base + 4 * s, 64);
      float ar = __shfl(area, base + 4 * (7 - s), 64);  // areas reversed
      float ps = __shfl(pred, base + 4 * s, 64);
      tot += as;
      ret += ps * ar;
    }
    if ((lane & 31) == 0) {
      int ql = (wave << 1) + (lane >> 5);
      out[qb + ql] = ret / tot;
    }
  }
}

extern "C" void kernel_launch(void* const* d_in, const int* in_sizes, int n_in,
                              void* d_out, int out_size, void* d_ws, size_t ws_size,
                              hipStream_t stream) {
  const float* inp   = (const float*)d_in[0];
  const float* coord = (const float*)d_in[1];
  const float* cell  = (const float*)d_in[2];
  const float* W0    = (const float*)d_in[3];
  const float* b0    = (const float*)d_in[4];
  const float* W1    = (const float*)d_in[5];
  const float* b1    = (const float*)d_in[6];
  const float* W2    = (const float*)d_in[7];
  const float* b2    = (const float*)d_in[8];
  const float* W3    = (const float*)d_in[9];
  const float* b3    = (const float*)d_in[10];
  unsigned short* ws = (unsigned short*)d_ws;
  float* out = (float*)d_out;

  const int Q = in_sizes[1] / 3;  // 131072
  hipLaunchKernelGGL(liif_prep, dim3((WS_TOTAL + 255) / 256), dim3(256), 0, stream,
                     inp, W0, W1, W2, W3, ws);
  hipLaunchKernelGGL(liif_main, dim3(Q / 8), dim3(256), 0, stream,
                     coord, cell, b0, b1, b2, b3, ws, out);
}

// Round 10
// 453.200 us; speedup vs baseline: 2.5205x; 2.5205x over previous
//
#include <hip/hip_runtime.h>

typedef __attribute__((ext_vector_type(8))) short s16x8;
typedef __attribute__((ext_vector_type(4))) float f32x4;
typedef __attribute__((ext_vector_type(2))) float f32x2;

// ---------------- bf16 helpers (RNE) ----------------
__device__ __forceinline__ unsigned short f2bf(float x) {
  unsigned u = __float_as_uint(x);
  u = (u + 0x7fffu + ((u >> 16) & 1u)) >> 16;
  return (unsigned short)u;
}
__device__ __forceinline__ unsigned cvt_pk_bf16(float a, float b) {
  unsigned r;
  asm("v_cvt_pk_bf16_f32 %0, %1, %2" : "=v"(r) : "v"(a), "v"(b));
  return r;
}
__device__ __forceinline__ float bflo(unsigned v) { return __uint_as_float(v << 16); }
__device__ __forceinline__ float bfhi(unsigned v) { return __uint_as_float(v & 0xffff0000u); }

// lgkm-only barrier: orders LDS across the block WITHOUT draining vmcnt --
// in-flight global B prefetches survive across it.
__device__ __forceinline__ void lgkm_barrier() {
  asm volatile("s_waitcnt lgkmcnt(0)" ::: "memory");
  __builtin_amdgcn_s_barrier();
  asm volatile("" ::: "memory");
}

// ---------------- ws layout (ushort units) ----------------
#define FEAT_OFF 0
#define W0F_OFF  2097152
#define W1F_OFF  (W0F_OFF + 24576)
#define W2F_OFF  (W1F_OFF + 65536)
#define W3P_OFF  (W2F_OFF + 65536)
#define WS_TOTAL (W3P_OFF + 512)

// H columns are stored permuted: position k' holds logical col
//   col_log(k') = (k'&0xC0) | ((k'&3)<<4) | ((k'>>2)&15)
__device__ __forceinline__ int col_log(int kp) {
  return (kp & 0xC0) | ((kp & 3) << 4) | ((kp >> 2) & 15);
}
// LDS h tile: 64x256 bf16, XOR-swizzled (T2) in place of padding:
//   idx(row,col) = row*256 + (col ^ ((row&7)<<3))
// bijective, preserves 16B/8B alignment. Correctness validated r7/r8.
__device__ __forceinline__ int hswz(int row, int col) {
  return row * 256 + (col ^ ((row & 7) << 3));
}

__global__ void liif_prep(const float* __restrict__ inp,
                          const float* __restrict__ W0,
                          const float* __restrict__ W1,
                          const float* __restrict__ W2,
                          const float* __restrict__ W3,
                          unsigned short* __restrict__ ws) {
  int tid = blockIdx.x * 256 + threadIdx.x;
  if (tid < 2097152) {
    int pos = tid >> 6, c = tid & 63;
    ws[FEAT_OFF + tid] = f2bf(inp[c * 32768 + pos]);
  } else if (tid < W1F_OFF) {
    int e = tid - W0F_OFF;
    int j = e & 7, L = (e >> 3) & 63, nt = (e >> 9) & 15, c = e >> 13;
    int k = c * 32 + (L >> 4) * 8 + j, n = nt * 16 + (L & 15);
    ws[tid] = (k < 71) ? f2bf(W0[k * 256 + n]) : (unsigned short)0;
  } else if (tid < W2F_OFF) {
    int e = tid - W1F_OFF;
    int j = e & 7, L = (e >> 3) & 63, nt = (e >> 9) & 15, c = e >> 13;
    int kp = c * 32 + (L >> 4) * 8 + j, n = nt * 16 + (L & 15);
    ws[tid] = f2bf(W1[col_log(kp) * 256 + n]);
  } else if (tid < W3P_OFF) {
    int e = tid - W2F_OFF;
    int j = e & 7, L = (e >> 3) & 63, nt = (e >> 9) & 15, c = e >> 13;
    int kp = c * 32 + (L >> 4) * 8 + j, n = nt * 16 + (L & 15);
    ws[tid] = f2bf(W2[col_log(kp) * 256 + n]);
  } else if (tid < W3P_OFF + 256) {
    int e = tid - W3P_OFF;
    float* w3p = (float*)(ws + W3P_OFF);
    w3p[e] = W3[col_log(e)];
  }
}

// One GEMM layer: 64 rows x 256 cols, 4 waves (wave = col-group).
// A: layer0 reads x at stride 104 (unswizzled); layers 1/2 read h via hswz.
// Bias folded into acc init. Epilogue: relu+cvt_pk+b64 swizzled stores.
// nb[] holds this layer's c=0 B-frags on entry; if PRE, exits with next
// layer's c=0 frags in flight (lgkm-only barriers keep vmcnt live).
template<int KC, bool PRE, bool SWZ>
__device__ __forceinline__ void run_layer(const unsigned short* __restrict__ Wf,
                                          const float* __restrict__ bias,
                                          const unsigned short* A,
                                          unsigned short* H,
                                          const unsigned short* __restrict__ Wnext,
                                          s16x8 (&nb)[4],
                                          int wave, int quad, int l16, int lane) {
  f32x4 acc[4][4];
#pragma unroll
  for (int ntl = 0; ntl < 4; ++ntl) {
    float bv = bias[(wave * 4 + ntl) * 16 + l16];
    f32x4 ai = (f32x4){bv, bv, bv, bv};
#pragma unroll
    for (int rt = 0; rt < 4; ++rt) acc[rt][ntl] = ai;
  }

  __builtin_amdgcn_s_setprio(1);
#pragma unroll
  for (int c = 0; c < KC; ++c) {
    s16x8 a[4];
#pragma unroll
    for (int rt = 0; rt < 4; ++rt) {
      int row = rt * 16 + l16, col = c * 32 + quad * 8;
      int idx = SWZ ? hswz(row, col) : row * 104 + col;
      a[rt] = *(const s16x8*)(A + idx);
    }
#pragma unroll
    for (int ntl = 0; ntl < 4; ++ntl) {
      int nt = wave * 4 + ntl;
      s16x8 b = (c == 0) ? nb[ntl]
                         : *(const s16x8*)(Wf + (((c * 16 + nt) * 64 + lane) << 3));
#pragma unroll
      for (int rt = 0; rt < 4; ++rt)
        acc[rt][ntl] = __builtin_amdgcn_mfma_f32_16x16x32_bf16(a[rt], b, acc[rt][ntl], 0, 0, 0);
    }
  }
  __builtin_amdgcn_s_setprio(0);

  if constexpr (PRE) {
#pragma unroll
    for (int ntl = 0; ntl < 4; ++ntl)
      nb[ntl] = *(const s16x8*)(Wnext + (((wave * 4 + ntl) * 64 + lane) << 3));
  }

  lgkm_barrier();  // all waves done reading A (aliases H); vmcnt stays live

  const int cb = wave * 64 + l16 * 4;  // col' base: 4 ntl-values contiguous
#pragma unroll
  for (int rt = 0; rt < 4; ++rt) {
#pragma unroll
    for (int i = 0; i < 4; ++i) {
      float v0 = fmaxf(acc[rt][0][i], 0.0f);
      float v1 = fmaxf(acc[rt][1][i], 0.0f);
      float v2 = fmaxf(acc[rt][2][i], 0.0f);
      float v3 = fmaxf(acc[rt][3][i], 0.0f);
      int r = rt * 16 + quad * 4 + i;
      uint2 pw = make_uint2(cvt_pk_bf16(v0, v1), cvt_pk_bf16(v2, v3));
      *(uint2*)(H + hswz(r, cb)) = pw;
    }
  }
  lgkm_barrier();  // H visible to all waves; prefetched vmcnt still live
}

// 256 threads, 64 rows (8 queries)/block. LDS = 64x256 bf16 = 32768 B ->
// 4 blocks/CU at the PROVEN (256,4) 128-reg envelope (64 VGPR + 64 AGPR,
// no spill -- r8's (256,5) capped regs at 96 and spilled the accumulators).
__global__ __launch_bounds__(256, 4)
void liif_main(const float* __restrict__ coord,
               const float* __restrict__ cell,
               const float* __restrict__ b0,
               const float* __restrict__ b1,
               const float* __restrict__ b2,
               const float* __restrict__ b3,
               const unsigned short* __restrict__ ws,
               float* __restrict__ out) {
  __shared__ __align__(16) unsigned short sm_h[64 * 256];  // 32768 B
  unsigned short* sm_x = sm_h;  // x[64][104] aliases the front during sampling/L0

  const unsigned short* feat = ws + FEAT_OFF;
  const float* W3p = (const float*)(ws + W3P_OFF);
  const int tid = threadIdx.x;
  const int lane = tid & 63;
  const int wave = tid >> 6;
  const int quad = lane >> 4;
  const int l16 = lane & 15;
  const int qb = blockIdx.x * 8;

  // layer0 c=0 B prefetch: in flight across the whole sampling phase
  s16x8 nb[4];
#pragma unroll
  for (int ntl = 0; ntl < 4; ++ntl)
    nb[ntl] = *(const s16x8*)(ws + W0F_OFF + (((wave * 4 + ntl) * 64 + lane) << 3));

  float area = 0.0f;  // held in registers; combined via shuffles at the end

  // ---------------- sampling: 4 threads per row, 16 channels each ----------------
  {
    const int row = tid >> 2, p = tid & 3;
    const int ql = row >> 3, s = row & 7;
    const int q = qb + ql;
    const float c0r = coord[q * 3 + 0], c1r = coord[q * 3 + 1], c2r = coord[q * 3 + 2];
    const float R = 0.03125f;  // rx=ry=rz = 1/32
    const float sh0 = ((s & 4) ? R : -R) + 1e-6f;
    const float sh1 = ((s & 2) ? R : -R) + 1e-6f;
    const float sh2 = ((s & 1) ? R : -R) + 1e-6f;
    const float LO = -1.0f + 1e-6f, HI = 1.0f - 1e-6f;
    float c0 = fminf(fmaxf(c0r + sh0, LO), HI);
    float c1 = fminf(fmaxf(c1r + sh1, LO), HI);
    float c2 = fminf(fmaxf(c2r + sh2, LO), HI);
    float z = (c0 + 1.0f) * 16.0f - 0.5f;
    float y = (c1 + 1.0f) * 16.0f - 0.5f;
    float x = (c2 + 1.0f) * 16.0f - 0.5f;
    float zf = floorf(z), yf = floorf(y), xf = floorf(x);
    float wz = z - zf, wy = y - yf, wx = x - xf;
    int z0 = min(max((int)zf, 0), 31), z1 = min(max((int)zf + 1, 0), 31);
    int y0 = min(max((int)yf, 0), 31), y1 = min(max((int)yf + 1, 0), 31);
    int x0 = min(max((int)xf, 0), 31), x1 = min(max((int)xf + 1, 0), 31);
    float wz0 = 1.0f - wz, wy0 = 1.0f - wy, wx0 = 1.0f - wx;

    float w[8] = { wz0 * wy0 * wx0, wz0 * wy0 * wx, wz0 * wy * wx0, wz0 * wy * wx,
                   wz  * wy0 * wx0, wz  * wy0 * wx, wz  * wy * wx0, wz  * wy * wx };
    int idx[8] = { (z0 * 32 + y0) * 32 + x0, (z0 * 32 + y0) * 32 + x1,
                   (z0 * 32 + y1) * 32 + x0, (z0 * 32 + y1) * 32 + x1,
                   (z1 * 32 + y0) * 32 + x0, (z1 * 32 + y0) * 32 + x1,
                   (z1 * 32 + y1) * 32 + x0, (z1 * 32 + y1) * 32 + x1 };

    // packed f32x2 accumulation (v_pk_fma_f32), r8-validated correct
    f32x2 acc2[8];
#pragma unroll
    for (int i = 0; i < 8; ++i) acc2[i] = (f32x2){0.f, 0.f};
#pragma unroll
    for (int corner = 0; corner < 8; ++corner) {
      const uint4* cp = (const uint4*)(feat + idx[corner] * 64 + p * 16);
      uint4 v0 = cp[0], v1 = cp[1];
      float wc = w[corner];
      f32x2 wc2 = (f32x2){wc, wc};
      unsigned vv[8] = { v0.x, v0.y, v0.z, v0.w, v1.x, v1.y, v1.z, v1.w };
#pragma unroll
      for (int d = 0; d < 8; ++d) {
        f32x2 xv = (f32x2){bflo(vv[d]), bfhi(vv[d])};
        acc2[d] += wc2 * xv;
      }
    }
    unsigned pw[8];
#pragma unroll
    for (int d = 0; d < 8; ++d)
      pw[d] = cvt_pk_bf16(acc2[d].x, acc2[d].y);
    uint4* dst = (uint4*)(&sm_x[row * 104 + p * 16]);
    dst[0] = make_uint4(pw[0], pw[1], pw[2], pw[3]);
    dst[1] = make_uint4(pw[4], pw[5], pw[6], pw[7]);

    if (p == 0) {
      const float step = 2.0f / 31.0f;
      float qc0 = wx0 * (-1.0f + step * x0) + wx * (-1.0f + step * x1);
      float qc1 = wy0 * (-1.0f + step * y0) + wy * (-1.0f + step * y1);
      float qc2 = wz0 * (-1.0f + step * z0) + wz * (-1.0f + step * z1);
      float rel0 = (c0r - qc0) * 32.0f;
      float rel1 = (c1r - qc1) * 32.0f;
      float rel2 = (c2r - qc2) * 32.0f;
      area = fabsf(rel0 * rel1 * rel2) + 1e-9f;
      float cl0 = cell[q * 3 + 0], cl1 = cell[q * 3 + 1], cl2 = cell[q * 3 + 2];
      float ssq = fminf(fmaxf(8.0f / (fabsf(cl0 * cl1 * cl2) + 1e-8f), 1.0f), 64.0f);
      unsigned tw0 = cvt_pk_bf16(rel0, rel1);
      unsigned tw1 = cvt_pk_bf16(rel2, cl0 * 32.0f);
      unsigned tw2 = cvt_pk_bf16(cl1 * 32.0f, cl2 * 32.0f);
      unsigned tw3 = cvt_pk_bf16(ssq, 0.0f);  // element 71 zero-padded
      uint4* d2 = (uint4*)(&sm_x[row * 104 + 64]);
      d2[0] = make_uint4(tw0, tw1, tw2, tw3);
      d2[1] = make_uint4(0, 0, 0, 0);  // cols 72..95 must be ZERO (K pad)
      d2[2] = make_uint4(0, 0, 0, 0);
      d2[3] = make_uint4(0, 0, 0, 0);
    }
  }
  lgkm_barrier();  // sampling writes visible; nb prefetch stays in flight

  // ---------------- MLP layers (bf16 MFMA, fp32 accum) ----------------
  run_layer<3, true,  false>(ws + W0F_OFF, b0, sm_x, sm_h, ws + W1F_OFF, nb, wave, quad, l16, lane);
  run_layer<8, true,  true >(ws + W1F_OFF, b1, sm_h, sm_h, ws + W2F_OFF, nb, wave, quad, l16, lane);
  run_layer<8, false, true >(ws + W2F_OFF, b2, sm_h, sm_h, nullptr,      nb, wave, quad, l16, lane);

  // ------- layer 3 (256->1) + area-weighted combine, all in registers -------
  {
    const int row = tid >> 2, p = tid & 3;
    float sum = 0.0f;
#pragma unroll
    for (int kk = 0; kk < 8; ++kk) {
      int col = p * 64 + kk * 8;
      const uint4 v = *(const uint4*)(sm_h + hswz(row, col));
      const float4 wa = *(const float4*)(W3p + col);
      const float4 wb = *(const float4*)(W3p + col + 4);
      sum += wa.x * bflo(v.x) + wa.y * bfhi(v.x);
      sum += wa.z * bflo(v.y) + wa.w * bfhi(v.y);
      sum += wb.x * bflo(v.z) + wb.y * bfhi(v.z);
      sum += wb.z * bflo(v.w) + wb.w * bfhi(v.w);
    }
    sum += __shfl_xor(sum, 1);
    sum += __shfl_xor(sum, 2);
    float pred = sum + b3[0];
    // wave covers rows 16w..16w+15 = queries 2w, 2w+1; shift s of the query
    // at lane-half 'base' lives at lane base+4s (its p==0 thread).
    const int base = lane & 32;
    float tot = 0.0f, ret = 0.0f;
#pragma unroll
    for (int s = 0; s < 8; ++s) {
      float as = __shfl(area, base + 4 * s, 64);
      float ar = __shfl(area, base + 4 * (7 - s), 64);  // areas reversed
      float ps = __shfl(pred, base + 4 * s, 64);
      tot += as;
      ret += ps * ar;
    }
    if ((lane & 31) == 0) {
      int ql = (wave << 1) + (lane >> 5);
      out[qb + ql] = ret / tot;
    }
  }
}

extern "C" void kernel_launch(void* const* d_in, const int* in_sizes, int n_in,
                              void* d_out, int out_size, void* d_ws, size_t ws_size,
                              hipStream_t stream) {
  const float* inp   = (const float*)d_in[0];
  const float* coord = (const float*)d_in[1];
  const float* cell  = (const float*)d_in[2];
  const float* W0    = (const float*)d_in[3];
  const float* b0    = (const float*)d_in[4];
  const float* W1    = (const float*)d_in[5];
  const float* b1    = (const float*)d_in[6];
  const float* W2    = (const float*)d_in[7];
  const float* b2    = (const float*)d_in[8];
  const float* W3    = (const float*)d_in[9];
  const float* b3    = (const float*)d_in[10];
  unsigned short* ws = (unsigned short*)d_ws;
  float* out = (float*)d_out;

  const int Q = in_sizes[1] / 3;  // 131072
  hipLaunchKernelGGL(liif_prep, dim3((WS_TOTAL + 255) / 256), dim3(256), 0, stream,
                     inp, W0, W1, W2, W3, ws);
  hipLaunchKernelGGL(liif_main, dim3(Q / 8), dim3(256), 0, stream,
                     coord, cell, b0, b1, b2, b3, ws, out);
}

// Round 11
// 429.544 us; speedup vs baseline: 2.6593x; 1.0551x over previous
//
#include <hip/hip_runtime.h>

typedef __attribute__((ext_vector_type(8))) short s16x8;
typedef __attribute__((ext_vector_type(4))) float f32x4;

// ---------------- bf16 helpers (RNE) ----------------
__device__ __forceinline__ unsigned short f2bf(float x) {
  unsigned u = __float_as_uint(x);
  u = (u + 0x7fffu + ((u >> 16) & 1u)) >> 16;
  return (unsigned short)u;
}
// v_cvt_pk_bf16_f32: dst.lo = bf16(a), dst.hi = bf16(b), RNE (same as f2bf)
__device__ __forceinline__ unsigned cvt_pk_bf16(float a, float b) {
  unsigned r;
  asm("v_cvt_pk_bf16_f32 %0, %1, %2" : "=v"(r) : "v"(a), "v"(b));
  return r;
}
__device__ __forceinline__ float bflo(unsigned v) { return __uint_as_float(v << 16); }
__device__ __forceinline__ float bfhi(unsigned v) { return __uint_as_float(v & 0xffff0000u); }

// lgkm-only barrier: orders LDS reads/writes across the block WITHOUT draining
// vmcnt -- in-flight global B prefetches survive across it (unlike __syncthreads,
// which hipcc compiles with a full vmcnt(0) drain).
__device__ __forceinline__ void lgkm_barrier() {
  asm volatile("s_waitcnt lgkmcnt(0)" ::: "memory");
  __builtin_amdgcn_s_barrier();
  asm volatile("" ::: "memory");
}

// ---------------- ws layout (ushort units) ----------------
#define FEAT_OFF 0
#define W0F_OFF  2097152
#define W1F_OFF  (W0F_OFF + 24576)
#define W2F_OFF  (W1F_OFF + 65536)
#define W3P_OFF  (W2F_OFF + 65536)
#define WS_TOTAL (W3P_OFF + 512)

// H is stored column-permuted: position k' holds logical col
//   col_log(k') = (k'&0xC0) | ((k'&3)<<4) | ((k'>>2)&15)
__device__ __forceinline__ int col_log(int kp) {
  return (kp & 0xC0) | ((kp & 3) << 4) | ((kp >> 2) & 15);
}

__global__ void liif_prep(const float* __restrict__ inp,
                          const float* __restrict__ W0,
                          const float* __restrict__ W1,
                          const float* __restrict__ W2,
                          const float* __restrict__ W3,
                          unsigned short* __restrict__ ws) {
  int tid = blockIdx.x * 256 + threadIdx.x;
  if (tid < 2097152) {
    int pos = tid >> 6, c = tid & 63;
    ws[FEAT_OFF + tid] = f2bf(inp[c * 32768 + pos]);
  } else if (tid < W1F_OFF) {
    int e = tid - W0F_OFF;
    int j = e & 7, L = (e >> 3) & 63, nt = (e >> 9) & 15, c = e >> 13;
    int k = c * 32 + (L >> 4) * 8 + j, n = nt * 16 + (L & 15);
    ws[tid] = (k < 71) ? f2bf(W0[k * 256 + n]) : (unsigned short)0;
  } else if (tid < W2F_OFF) {
    int e = tid - W1F_OFF;
    int j = e & 7, L = (e >> 3) & 63, nt = (e >> 9) & 15, c = e >> 13;
    int kp = c * 32 + (L >> 4) * 8 + j, n = nt * 16 + (L & 15);
    ws[tid] = f2bf(W1[col_log(kp) * 256 + n]);
  } else if (tid < W3P_OFF) {
    int e = tid - W2F_OFF;
    int j = e & 7, L = (e >> 3) & 63, nt = (e >> 9) & 15, c = e >> 13;
    int kp = c * 32 + (L >> 4) * 8 + j, n = nt * 16 + (L & 15);
    ws[tid] = f2bf(W2[col_log(kp) * 256 + n]);
  } else if (tid < W3P_OFF + 256) {
    int e = tid - W3P_OFF;
    float* w3p = (float*)(ws + W3P_OFF);
    w3p[e] = W3[col_log(e)];
  }
}

// One GEMM layer: rows 0..63 (A in LDS, bf16), cols 0..255 (B frags in global),
// out = relu(acc) -> H (LDS, stride 264, COLUMN-PERMUTED layout).
// BIAS IS FOLDED INTO THE ACCUMULATOR INIT: C-fragment layout puts all 4 acc
// regs of a thread in ONE column, so acc starts at {bv,bv,bv,bv}.
// nb[] holds THIS layer's c=0 B-frags on entry; if PRE, exits with the NEXT
// layer's c=0 frags in flight (lgkm-only barriers keep vmcnt live across).
template<int KC, bool PRE>
__device__ __forceinline__ void run_layer(const unsigned short* __restrict__ Wf,
                                          const float* __restrict__ bias,
                                          const unsigned short* A, int astride,
                                          unsigned short* H,
                                          const unsigned short* __restrict__ Wnext,
                                          s16x8 (&nb)[4],
                                          int wave, int quad, int l16, int lane) {
  f32x4 acc[4][4];
#pragma unroll
  for (int ntl = 0; ntl < 4; ++ntl) {
    float bv = bias[(wave * 4 + ntl) * 16 + l16];
    f32x4 ai = (f32x4){bv, bv, bv, bv};
#pragma unroll
    for (int rt = 0; rt < 4; ++rt) acc[rt][ntl] = ai;
  }

  __builtin_amdgcn_s_setprio(1);
#pragma unroll
  for (int c = 0; c < KC; ++c) {
    s16x8 a[4];
#pragma unroll
    for (int rt = 0; rt < 4; ++rt)
      a[rt] = *(const s16x8*)(A + (rt * 16 + l16) * astride + c * 32 + quad * 8);
#pragma unroll
    for (int ntl = 0; ntl < 4; ++ntl) {
      int nt = wave * 4 + ntl;
      s16x8 b = (c == 0) ? nb[ntl]
                         : *(const s16x8*)(Wf + (((c * 16 + nt) * 64 + lane) << 3));
#pragma unroll
      for (int rt = 0; rt < 4; ++rt)
        acc[rt][ntl] = __builtin_amdgcn_mfma_f32_16x16x32_bf16(a[rt], b, acc[rt][ntl], 0, 0, 0);
    }
  }
  __builtin_amdgcn_s_setprio(0);

  // issue NEXT layer's c=0 B loads now: latency hides under epilogue + barriers
  if constexpr (PRE) {
#pragma unroll
    for (int ntl = 0; ntl < 4; ++ntl)
      nb[ntl] = *(const s16x8*)(Wnext + (((wave * 4 + ntl) * 64 + lane) << 3));
  }

  lgkm_barrier();  // all waves done reading A (may alias H); vmcnt stays live

  const int cbase = wave * 64 + l16 * 4;  // col' base: 4 ntl-values contiguous
#pragma unroll
  for (int rt = 0; rt < 4; ++rt) {
#pragma unroll
    for (int i = 0; i < 4; ++i) {
      float v0 = fmaxf(acc[rt][0][i], 0.0f);
      float v1 = fmaxf(acc[rt][1][i], 0.0f);
      float v2 = fmaxf(acc[rt][2][i], 0.0f);
      float v3 = fmaxf(acc[rt][3][i], 0.0f);
      int r = rt * 16 + quad * 4 + i;
      uint2 pw = make_uint2(cvt_pk_bf16(v0, v1), cvt_pk_bf16(v2, v3));
      *(uint2*)(H + r * 264 + cbase) = pw;
    }
  }
  lgkm_barrier();  // H visible to all waves; prefetched vmcnt still live
}

__global__ __launch_bounds__(256, 4)
void liif_main(const float* __restrict__ coord,
               const float* __restrict__ cell,
               const float* __restrict__ b0,
               const float* __restrict__ b1,
               const float* __restrict__ b2,
               const float* __restrict__ b3,
               const unsigned short* __restrict__ ws,
               float* __restrict__ out) {
  // LDS: h[64][264] bf16 (stride 264). x[64][104] ALIASES the front of h:
  // run_layer's read->barrier->write discipline makes layer0's in-place-style
  // overwrite of the x region safe. 34.3 KB total -> 4 blocks/CU.
  __shared__ __align__(16) unsigned short sm_h[64 * 264];
  __shared__ float sm_area[64];
  __shared__ float sm_pred[64];
  unsigned short* sm_x = sm_h;  // stride 104 during sampling/layer0

  const unsigned short* feat = ws + FEAT_OFF;
  const int tid = threadIdx.x;
  const int lane = tid & 63;
  const int wave = tid >> 6;
  const int quad = lane >> 4;
  const int l16 = lane & 15;

  // layer0 c=0 B prefetch: in flight across the whole sampling phase
  s16x8 nb[4];
#pragma unroll
  for (int ntl = 0; ntl < 4; ++ntl)
    nb[ntl] = *(const s16x8*)(ws + W0F_OFF + (((wave * 4 + ntl) * 64 + lane) << 3));

  // ---------------- sampling: 4 threads per row, 16 channels each ----------------
  {
    const int row = tid >> 2, p = tid & 3;
    const int ql = row >> 3, s = row & 7;
    const int q = blockIdx.x * 8 + ql;
    const float c0r = coord[q * 3 + 0], c1r = coord[q * 3 + 1], c2r = coord[q * 3 + 2];
    const float R = 0.03125f;  // rx=ry=rz = 1/32
    const float sh0 = ((s & 4) ? R : -R) + 1e-6f;
    const float sh1 = ((s & 2) ? R : -R) + 1e-6f;
    const float sh2 = ((s & 1) ? R : -R) + 1e-6f;
    const float LO = -1.0f + 1e-6f, HI = 1.0f - 1e-6f;
    float c0 = fminf(fmaxf(c0r + sh0, LO), HI);
    float c1 = fminf(fmaxf(c1r + sh1, LO), HI);
    float c2 = fminf(fmaxf(c2r + sh2, LO), HI);
    // channel0 -> z/D axis, channel1 -> y/H, channel2 -> x/W
    float z = (c0 + 1.0f) * 16.0f - 0.5f;
    float y = (c1 + 1.0f) * 16.0f - 0.5f;
    float x = (c2 + 1.0f) * 16.0f - 0.5f;
    float zf = floorf(z), yf = floorf(y), xf = floorf(x);
    float wz = z - zf, wy = y - yf, wx = x - xf;
    int z0 = min(max((int)zf, 0), 31), z1 = min(max((int)zf + 1, 0), 31);
    int y0 = min(max((int)yf, 0), 31), y1 = min(max((int)yf + 1, 0), 31);
    int x0 = min(max((int)xf, 0), 31), x1 = min(max((int)xf + 1, 0), 31);
    float wz0 = 1.0f - wz, wy0 = 1.0f - wy, wx0 = 1.0f - wx;

    float w[8] = { wz0 * wy0 * wx0, wz0 * wy0 * wx, wz0 * wy * wx0, wz0 * wy * wx,
                   wz  * wy0 * wx0, wz  * wy0 * wx, wz  * wy * wx0, wz  * wy * wx };
    int idx[8] = { (z0 * 32 + y0) * 32 + x0, (z0 * 32 + y0) * 32 + x1,
                   (z0 * 32 + y1) * 32 + x0, (z0 * 32 + y1) * 32 + x1,
                   (z1 * 32 + y0) * 32 + x0, (z1 * 32 + y0) * 32 + x1,
                   (z1 * 32 + y1) * 32 + x0, (z1 * 32 + y1) * 32 + x1 };

    float acc[16];
#pragma unroll
    for (int i = 0; i < 16; ++i) acc[i] = 0.0f;
#pragma unroll
    for (int corner = 0; corner < 8; ++corner) {
      const uint4* cp = (const uint4*)(feat + idx[corner] * 64 + p * 16);
      uint4 v0 = cp[0], v1 = cp[1];
      float wc = w[corner];
      unsigned vv[8] = { v0.x, v0.y, v0.z, v0.w, v1.x, v1.y, v1.z, v1.w };
#pragma unroll
      for (int d = 0; d < 8; ++d) {
        acc[2 * d]     += wc * bflo(vv[d]);
        acc[2 * d + 1] += wc * bfhi(vv[d]);
      }
    }
    unsigned pw[8];
#pragma unroll
    for (int d = 0; d < 8; ++d)
      pw[d] = cvt_pk_bf16(acc[2 * d], acc[2 * d + 1]);
    uint4* dst = (uint4*)(&sm_x[row * 104 + p * 16]);
    dst[0] = make_uint4(pw[0], pw[1], pw[2], pw[3]);
    dst[1] = make_uint4(pw[4], pw[5], pw[6], pw[7]);

    if (p == 0) {
      const float step = 2.0f / 31.0f;
      // q_coord channel mixing as in reference: ch0 from x-interp, ch2 from z-interp
      float qc0 = wx0 * (-1.0f + step * x0) + wx * (-1.0f + step * x1);
      float qc1 = wy0 * (-1.0f + step * y0) + wy * (-1.0f + step * y1);
      float qc2 = wz0 * (-1.0f + step * z0) + wz * (-1.0f + step * z1);
      float rel0 = (c0r - qc0) * 32.0f;
      float rel1 = (c1r - qc1) * 32.0f;
      float rel2 = (c2r - qc2) * 32.0f;
      sm_area[row] = fabsf(rel0 * rel1 * rel2) + 1e-9f;
      float cl0 = cell[q * 3 + 0], cl1 = cell[q * 3 + 1], cl2 = cell[q * 3 + 2];
      float ssq = fminf(fmaxf(8.0f / (fabsf(cl0 * cl1 * cl2) + 1e-8f), 1.0f), 64.0f);
      unsigned tw0 = cvt_pk_bf16(rel0, rel1);
      unsigned tw1 = cvt_pk_bf16(rel2, cl0 * 32.0f);
      unsigned tw2 = cvt_pk_bf16(cl1 * 32.0f, cl2 * 32.0f);
      unsigned tw3 = cvt_pk_bf16(ssq, 0.0f);  // element 71 zero-padded
      uint4* d2 = (uint4*)(&sm_x[row * 104 + 64]);
      d2[0] = make_uint4(tw0, tw1, tw2, tw3);
      d2[1] = make_uint4(0, 0, 0, 0);
      d2[2] = make_uint4(0, 0, 0, 0);
      d2[3] = make_uint4(0, 0, 0, 0);
    }
  }
  lgkm_barrier();  // sampling writes visible; nb prefetch stays in flight

  // ---------------- MLP layers (bf16 MFMA, fp32 accum) ----------------
  run_layer<3, true >(ws + W0F_OFF, b0, sm_x, 104, sm_h, ws + W1F_OFF, nb, wave, quad, l16, lane);
  run_layer<8, true >(ws + W1F_OFF, b1, sm_h, 264, sm_h, ws + W2F_OFF, nb, wave, quad, l16, lane);
  run_layer<8, false>(ws + W2F_OFF, b2, sm_h, 264, sm_h, nullptr,      nb, wave, quad, l16, lane);

  // ---------------- layer 3: 256 -> 1 (fp32 VALU, permuted W3 copy) ----------------
  {
    const int row = tid >> 2, p = tid & 3;
    const unsigned short* hp = sm_h + row * 264 + p * 64;
    const float* W3p = (const float*)(ws + W3P_OFF);
    float sum = 0.0f;
#pragma unroll
    for (int kk = 0; kk < 8; ++kk) {
      const uint4 v = *(const uint4*)(hp + kk * 8);
      const float4 wa = *(const float4*)(W3p + p * 64 + kk * 8);
      const float4 wb = *(const float4*)(W3p + p * 64 + kk * 8 + 4);
      sum += wa.x * bflo(v.x) + wa.y * bfhi(v.x);
      sum += wa.z * bflo(v.y) + wa.w * bfhi(v.y);
      sum += wb.x * bflo(v.z) + wb.y * bfhi(v.z);
      sum += wb.z * bflo(v.w) + wb.w * bfhi(v.w);
    }
    sum += __shfl_xor(sum, 1);
    sum += __shfl_xor(sum, 2);
    if (p == 0) sm_pred[row] = sum + b3[0];
  }
  lgkm_barrier();

  // ---------------- area-weighted combine (areas reversed) ----------------
  if (tid < 8) {
    const int ql = tid;
    float tot = 0.0f, ret = 0.0f;
#pragma unroll
    for (int s = 0; s < 8; ++s) tot += sm_area[ql * 8 + s];
#pragma unroll
    for (int s = 0; s < 8; ++s) ret += sm_pred[ql * 8 + s] * sm_area[ql * 8 + (7 - s)];
    out[blockIdx.x * 8 + ql] = ret / tot;
  }
}

extern "C" void kernel_launch(void* const* d_in, const int* in_sizes, int n_in,
                              void* d_out, int out_size, void* d_ws, size_t ws_size,
                              hipStream_t stream) {
  const float* inp   = (const float*)d_in[0];
  const float* coord = (const float*)d_in[1];
  const float* cell  = (const float*)d_in[2];
  const float* W0    = (const float*)d_in[3];
  const float* b0    = (const float*)d_in[4];
  const float* W1    = (const float*)d_in[5];
  const float* b1    = (const float*)d_in[6];
  const float* W2    = (const float*)d_in[7];
  const float* b2    = (const float*)d_in[8];
  const float* W3    = (const float*)d_in[9];
  const float* b3    = (const float*)d_in[10];
  unsigned short* ws = (unsigned short*)d_ws;
  float* out = (float*)d_out;

  const int Q = in_sizes[1] / 3;  // 131072
  hipLaunchKernelGGL(liif_prep, dim3((WS_TOTAL + 255) / 256), dim3(256), 0, stream,
                     inp, W0, W1, W2, W3, ws);
  hipLaunchKernelGGL(liif_main, dim3(Q / 8), dim3(256), 0, stream,
                     coord, cell, b0, b1, b2, b3, ws, out);
}

// Round 12
// 419.459 us; speedup vs baseline: 2.7232x; 1.0240x over previous
//
#include <hip/hip_runtime.h>

typedef __attribute__((ext_vector_type(8))) short s16x8;
typedef __attribute__((ext_vector_type(4))) float f32x4;

// ---------------- bf16 helpers (RNE) ----------------
__device__ __forceinline__ unsigned short f2bf(float x) {
  unsigned u = __float_as_uint(x);
  u = (u + 0x7fffu + ((u >> 16) & 1u)) >> 16;
  return (unsigned short)u;
}
// v_cvt_pk_bf16_f32: dst.lo = bf16(a), dst.hi = bf16(b), RNE (same as f2bf)
__device__ __forceinline__ unsigned cvt_pk_bf16(float a, float b) {
  unsigned r;
  asm("v_cvt_pk_bf16_f32 %0, %1, %2" : "=v"(r) : "v"(a), "v"(b));
  return r;
}
__device__ __forceinline__ float bflo(unsigned v) { return __uint_as_float(v << 16); }
__device__ __forceinline__ float bfhi(unsigned v) { return __uint_as_float(v & 0xffff0000u); }

// lgkm-only barrier: orders LDS reads/writes across the block WITHOUT draining
// vmcnt -- in-flight global B prefetches survive across it (unlike __syncthreads,
// which hipcc compiles with a full vmcnt(0) drain).
__device__ __forceinline__ void lgkm_barrier() {
  asm volatile("s_waitcnt lgkmcnt(0)" ::: "memory");
  __builtin_amdgcn_s_barrier();
  asm volatile("" ::: "memory");
}

// ---------------- ws layout (ushort units) ----------------
#define FEAT_OFF 0
#define W0F_OFF  2097152
#define W1F_OFF  (W0F_OFF + 24576)
#define W2F_OFF  (W1F_OFF + 65536)
#define W3P_OFF  (W2F_OFF + 65536)
#define WS_TOTAL (W3P_OFF + 512)

// H is stored column-permuted: position k' holds logical col
//   col_log(k') = (k'&0xC0) | ((k'&3)<<4) | ((k'>>2)&15)
__device__ __forceinline__ int col_log(int kp) {
  return (kp & 0xC0) | ((kp & 3) << 4) | ((kp >> 2) & 15);
}

// prep: blocks 0..511 transpose feat via LDS tiles (coalesced both sides --
// the old per-element path read inp with 128KB lane stride: ~134MB overfetch,
// ~21us of the ~26us prep time). Blocks 512+ do the weight reformat as before.
__global__ void liif_prep(const float* __restrict__ inp,
                          const float* __restrict__ W0,
                          const float* __restrict__ W1,
                          const float* __restrict__ W2,
                          const float* __restrict__ W3,
                          unsigned short* __restrict__ ws) {
  if (blockIdx.x < 512) {
    // 64(pos) x 64(chan) tile: posb = blockIdx*64
    __shared__ unsigned short tile[64 * 66];  // [c][pos], pad 66 vs bank hits
    const int tid = threadIdx.x;
    const int posb = blockIdx.x * 64;
    // phase 1: coalesced float4 reads. thread -> c = (tid>>4)+16i, pos4 = (tid&15)*4
    const int p4 = (tid & 15) * 4;
#pragma unroll
    for (int i = 0; i < 4; ++i) {
      int c = (tid >> 4) + 16 * i;
      const float4 v = *(const float4*)(inp + c * 32768 + posb + p4);
      unsigned short* t = &tile[c * 66 + p4];
      t[0] = f2bf(v.x); t[1] = f2bf(v.y); t[2] = f2bf(v.z); t[3] = f2bf(v.w);
    }
    __syncthreads();
    // phase 2: thread writes 16 consecutive shorts at ws[posb*64 + tid*16]
    //   element e = tid*16+j -> pos_local = tid>>2, c = (tid&3)*16+j
    const int pl = tid >> 2, c0 = (tid & 3) * 16;
    unsigned pw[8];
#pragma unroll
    for (int m = 0; m < 8; ++m) {
      unsigned lo = tile[(c0 + 2 * m) * 66 + pl];
      unsigned hi = tile[(c0 + 2 * m + 1) * 66 + pl];
      pw[m] = lo | (hi << 16);
    }
    uint4* dst = (uint4*)(ws + posb * 64 + tid * 16);
    dst[0] = make_uint4(pw[0], pw[1], pw[2], pw[3]);
    dst[1] = make_uint4(pw[4], pw[5], pw[6], pw[7]);
    return;
  }

  int tid = W0F_OFF + (blockIdx.x - 512) * 256 + threadIdx.x;
  if (tid < W1F_OFF) {
    int e = tid - W0F_OFF;
    int j = e & 7, L = (e >> 3) & 63, nt = (e >> 9) & 15, c = e >> 13;
    int k = c * 32 + (L >> 4) * 8 + j, n = nt * 16 + (L & 15);
    ws[tid] = (k < 71) ? f2bf(W0[k * 256 + n]) : (unsigned short)0;
  } else if (tid < W2F_OFF) {
    int e = tid - W1F_OFF;
    int j = e & 7, L = (e >> 3) & 63, nt = (e >> 9) & 15, c = e >> 13;
    int kp = c * 32 + (L >> 4) * 8 + j, n = nt * 16 + (L & 15);
    ws[tid] = f2bf(W1[col_log(kp) * 256 + n]);
  } else if (tid < W3P_OFF) {
    int e = tid - W2F_OFF;
    int j = e & 7, L = (e >> 3) & 63, nt = (e >> 9) & 15, c = e >> 13;
    int kp = c * 32 + (L >> 4) * 8 + j, n = nt * 16 + (L & 15);
    ws[tid] = f2bf(W2[col_log(kp) * 256 + n]);
  } else if (tid < W3P_OFF + 256) {
    int e = tid - W3P_OFF;
    float* w3p = (float*)(ws + W3P_OFF);
    w3p[e] = W3[col_log(e)];
  }
}

// One GEMM layer: rows 0..63 (A in LDS, bf16), cols 0..255 (B frags in global),
// out = relu(acc) -> H (LDS, stride 264, COLUMN-PERMUTED layout).
// BIAS IS FOLDED INTO THE ACCUMULATOR INIT: C-fragment layout puts all 4 acc
// regs of a thread in ONE column, so acc starts at {bv,bv,bv,bv}.
// nb[] holds THIS layer's c=0 B-frags on entry; if PRE, exits with the NEXT
// layer's c=0 frags in flight (lgkm-only barriers keep vmcnt live across).
template<int KC, bool PRE>
__device__ __forceinline__ void run_layer(const unsigned short* __restrict__ Wf,
                                          const float* __restrict__ bias,
                                          const unsigned short* A, int astride,
                                          unsigned short* H,
                                          const unsigned short* __restrict__ Wnext,
                                          s16x8 (&nb)[4],
                                          int wave, int quad, int l16, int lane) {
  f32x4 acc[4][4];
#pragma unroll
  for (int ntl = 0; ntl < 4; ++ntl) {
    float bv = bias[(wave * 4 + ntl) * 16 + l16];
    f32x4 ai = (f32x4){bv, bv, bv, bv};
#pragma unroll
    for (int rt = 0; rt < 4; ++rt) acc[rt][ntl] = ai;
  }

  __builtin_amdgcn_s_setprio(1);
#pragma unroll
  for (int c = 0; c < KC; ++c) {
    s16x8 a[4];
#pragma unroll
    for (int rt = 0; rt < 4; ++rt)
      a[rt] = *(const s16x8*)(A + (rt * 16 + l16) * astride + c * 32 + quad * 8);
#pragma unroll
    for (int ntl = 0; ntl < 4; ++ntl) {
      int nt = wave * 4 + ntl;
      s16x8 b = (c == 0) ? nb[ntl]
                         : *(const s16x8*)(Wf + (((c * 16 + nt) * 64 + lane) << 3));
#pragma unroll
      for (int rt = 0; rt < 4; ++rt)
        acc[rt][ntl] = __builtin_amdgcn_mfma_f32_16x16x32_bf16(a[rt], b, acc[rt][ntl], 0, 0, 0);
    }
  }
  __builtin_amdgcn_s_setprio(0);

  // issue NEXT layer's c=0 B loads now: latency hides under epilogue + barriers
  if constexpr (PRE) {
#pragma unroll
    for (int ntl = 0; ntl < 4; ++ntl)
      nb[ntl] = *(const s16x8*)(Wnext + (((wave * 4 + ntl) * 64 + lane) << 3));
  }

  lgkm_barrier();  // all waves done reading A (may alias H); vmcnt stays live

  const int cbase = wave * 64 + l16 * 4;  // col' base: 4 ntl-values contiguous
#pragma unroll
  for (int rt = 0; rt < 4; ++rt) {
#pragma unroll
    for (int i = 0; i < 4; ++i) {
      float v0 = fmaxf(acc[rt][0][i], 0.0f);
      float v1 = fmaxf(acc[rt][1][i], 0.0f);
      float v2 = fmaxf(acc[rt][2][i], 0.0f);
      float v3 = fmaxf(acc[rt][3][i], 0.0f);
      int r = rt * 16 + quad * 4 + i;
      uint2 pw = make_uint2(cvt_pk_bf16(v0, v1), cvt_pk_bf16(v2, v3));
      *(uint2*)(H + r * 264 + cbase) = pw;
    }
  }
  lgkm_barrier();  // H visible to all waves; prefetched vmcnt still live
}

__global__ __launch_bounds__(256, 4)
void liif_main(const float* __restrict__ coord,
               const float* __restrict__ cell,
               const float* __restrict__ b0,
               const float* __restrict__ b1,
               const float* __restrict__ b2,
               const float* __restrict__ b3,
               const unsigned short* __restrict__ ws,
               float* __restrict__ out) {
  // LDS: h[64][264] bf16 (stride 264). x[64][104] ALIASES the front of h:
  // run_layer's read->barrier->write discipline makes layer0's in-place-style
  // overwrite of the x region safe. 34.3 KB total -> 4 blocks/CU.
  __shared__ __align__(16) unsigned short sm_h[64 * 264];
  __shared__ float sm_area[64];
  __shared__ float sm_pred[64];
  unsigned short* sm_x = sm_h;  // stride 104 during sampling/layer0

  const unsigned short* feat = ws + FEAT_OFF;
  const int tid = threadIdx.x;
  const int lane = tid & 63;
  const int wave = tid >> 6;
  const int quad = lane >> 4;
  const int l16 = lane & 15;

  // layer0 c=0 B prefetch: in flight across the whole sampling phase
  s16x8 nb[4];
#pragma unroll
  for (int ntl = 0; ntl < 4; ++ntl)
    nb[ntl] = *(const s16x8*)(ws + W0F_OFF + (((wave * 4 + ntl) * 64 + lane) << 3));

  // ---------------- sampling: 4 threads per row, 16 channels each ----------------
  {
    const int row = tid >> 2, p = tid & 3;
    const int ql = row >> 3, s = row & 7;
    const int q = blockIdx.x * 8 + ql;
    const float c0r = coord[q * 3 + 0], c1r = coord[q * 3 + 1], c2r = coord[q * 3 + 2];
    const float R = 0.03125f;  // rx=ry=rz = 1/32
    const float sh0 = ((s & 4) ? R : -R) + 1e-6f;
    const float sh1 = ((s & 2) ? R : -R) + 1e-6f;
    const float sh2 = ((s & 1) ? R : -R) + 1e-6f;
    const float LO = -1.0f + 1e-6f, HI = 1.0f - 1e-6f;
    float c0 = fminf(fmaxf(c0r + sh0, LO), HI);
    float c1 = fminf(fmaxf(c1r + sh1, LO), HI);
    float c2 = fminf(fmaxf(c2r + sh2, LO), HI);
    // channel0 -> z/D axis, channel1 -> y/H, channel2 -> x/W
    float z = (c0 + 1.0f) * 16.0f - 0.5f;
    float y = (c1 + 1.0f) * 16.0f - 0.5f;
    float x = (c2 + 1.0f) * 16.0f - 0.5f;
    float zf = floorf(z), yf = floorf(y), xf = floorf(x);
    float wz = z - zf, wy = y - yf, wx = x - xf;
    int z0 = min(max((int)zf, 0), 31), z1 = min(max((int)zf + 1, 0), 31);
    int y0 = min(max((int)yf, 0), 31), y1 = min(max((int)yf + 1, 0), 31);
    int x0 = min(max((int)xf, 0), 31), x1 = min(max((int)xf + 1, 0), 31);
    float wz0 = 1.0f - wz, wy0 = 1.0f - wy, wx0 = 1.0f - wx;

    float w[8] = { wz0 * wy0 * wx0, wz0 * wy0 * wx, wz0 * wy * wx0, wz0 * wy * wx,
                   wz  * wy0 * wx0, wz  * wy0 * wx, wz  * wy * wx0, wz  * wy * wx };
    int idx[8] = { (z0 * 32 + y0) * 32 + x0, (z0 * 32 + y0) * 32 + x1,
                   (z0 * 32 + y1) * 32 + x0, (z0 * 32 + y1) * 32 + x1,
                   (z1 * 32 + y0) * 32 + x0, (z1 * 32 + y0) * 32 + x1,
                   (z1 * 32 + y1) * 32 + x0, (z1 * 32 + y1) * 32 + x1 };

    float acc[16];
#pragma unroll
    for (int i = 0; i < 16; ++i) acc[i] = 0.0f;
#pragma unroll
    for (int corner = 0; corner < 8; ++corner) {
      const uint4* cp = (const uint4*)(feat + idx[corner] * 64 + p * 16);
      uint4 v0 = cp[0], v1 = cp[1];
      float wc = w[corner];
      unsigned vv[8] = { v0.x, v0.y, v0.z, v0.w, v1.x, v1.y, v1.z, v1.w };
#pragma unroll
      for (int d = 0; d < 8; ++d) {
        acc[2 * d]     += wc * bflo(vv[d]);
        acc[2 * d + 1] += wc * bfhi(vv[d]);
      }
    }
    unsigned pw[8];
#pragma unroll
    for (int d = 0; d < 8; ++d)
      pw[d] = cvt_pk_bf16(acc[2 * d], acc[2 * d + 1]);
    uint4* dst = (uint4*)(&sm_x[row * 104 + p * 16]);
    dst[0] = make_uint4(pw[0], pw[1], pw[2], pw[3]);
    dst[1] = make_uint4(pw[4], pw[5], pw[6], pw[7]);

    if (p == 0) {
      const float step = 2.0f / 31.0f;
      // q_coord channel mixing as in reference: ch0 from x-interp, ch2 from z-interp
      float qc0 = wx0 * (-1.0f + step * x0) + wx * (-1.0f + step * x1);
      float qc1 = wy0 * (-1.0f + step * y0) + wy * (-1.0f + step * y1);
      float qc2 = wz0 * (-1.0f + step * z0) + wz * (-1.0f + step * z1);
      float rel0 = (c0r - qc0) * 32.0f;
      float rel1 = (c1r - qc1) * 32.0f;
      float rel2 = (c2r - qc2) * 32.0f;
      sm_area[row] = fabsf(rel0 * rel1 * rel2) + 1e-9f;
      float cl0 = cell[q * 3 + 0], cl1 = cell[q * 3 + 1], cl2 = cell[q * 3 + 2];
      float ssq = fminf(fmaxf(8.0f / (fabsf(cl0 * cl1 * cl2) + 1e-8f), 1.0f), 64.0f);
      unsigned tw0 = cvt_pk_bf16(rel0, rel1);
      unsigned tw1 = cvt_pk_bf16(rel2, cl0 * 32.0f);
      unsigned tw2 = cvt_pk_bf16(cl1 * 32.0f, cl2 * 32.0f);
      unsigned tw3 = cvt_pk_bf16(ssq, 0.0f);  // element 71 zero-padded
      uint4* d2 = (uint4*)(&sm_x[row * 104 + 64]);
      d2[0] = make_uint4(tw0, tw1, tw2, tw3);
      d2[1] = make_uint4(0, 0, 0, 0);
      d2[2] = make_uint4(0, 0, 0, 0);
      d2[3] = make_uint4(0, 0, 0, 0);
    }
  }
  lgkm_barrier();  // sampling writes visible; nb prefetch stays in flight

  // ---------------- MLP layers (bf16 MFMA, fp32 accum) ----------------
  run_layer<3, true >(ws + W0F_OFF, b0, sm_x, 104, sm_h, ws + W1F_OFF, nb, wave, quad, l16, lane);
  run_layer<8, true >(ws + W1F_OFF, b1, sm_h, 264, sm_h, ws + W2F_OFF, nb, wave, quad, l16, lane);
  run_layer<8, false>(ws + W2F_OFF, b2, sm_h, 264, sm_h, nullptr,      nb, wave, quad, l16, lane);

  // ---------------- layer 3: 256 -> 1 (fp32 VALU, permuted W3 copy) ----------------
  {
    const int row = tid >> 2, p = tid & 3;
    const unsigned short* hp = sm_h + row * 264 + p * 64;
    const float* W3p = (const float*)(ws + W3P_OFF);
    float sum = 0.0f;
#pragma unroll
    for (int kk = 0; kk < 8; ++kk) {
      const uint4 v = *(const uint4*)(hp + kk * 8);
      const float4 wa = *(const float4*)(W3p + p * 64 + kk * 8);
      const float4 wb = *(const float4*)(W3p + p * 64 + kk * 8 + 4);
      sum += wa.x * bflo(v.x) + wa.y * bfhi(v.x);
      sum += wa.z * bflo(v.y) + wa.w * bfhi(v.y);
      sum += wb.x * bflo(v.z) + wb.y * bfhi(v.z);
      sum += wb.z * bflo(v.w) + wb.w * bfhi(v.w);
    }
    sum += __shfl_xor(sum, 1);
    sum += __shfl_xor(sum, 2);
    if (p == 0) sm_pred[row] = sum + b3[0];
  }
  lgkm_barrier();

  // ---------------- area-weighted combine (areas reversed) ----------------
  if (tid < 8) {
    const int ql = tid;
    float tot = 0.0f, ret = 0.0f;
#pragma unroll
    for (int s = 0; s < 8; ++s) tot += sm_area[ql * 8 + s];
#pragma unroll
    for (int s = 0; s < 8; ++s) ret += sm_pred[ql * 8 + s] * sm_area[ql * 8 + (7 - s)];
    out[blockIdx.x * 8 + ql] = ret / tot;
  }
}

extern "C" void kernel_launch(void* const* d_in, const int* in_sizes, int n_in,
                              void* d_out, int out_size, void* d_ws, size_t ws_size,
                              hipStream_t stream) {
  const float* inp   = (const float*)d_in[0];
  const float* coord = (const float*)d_in[1];
  const float* cell  = (const float*)d_in[2];
  const float* W0    = (const float*)d_in[3];
  const float* b0    = (const float*)d_in[4];
  const float* W1    = (const float*)d_in[5];
  const float* b1    = (const float*)d_in[6];
  const float* W2    = (const float*)d_in[7];
  const float* b2    = (const float*)d_in[8];
  const float* W3    = (const float*)d_in[9];
  const float* b3    = (const float*)d_in[10];
  unsigned short* ws = (unsigned short*)d_ws;
  float* out = (float*)d_out;

  const int Q = in_sizes[1] / 3;  // 131072
  // 512 feat-transpose tiles + 610 weight blocks (156160 weight elements / 256)
  hipLaunchKernelGGL(liif_prep, dim3(512 + (WS_TOTAL - W0F_OFF + 255) / 256), dim3(256), 0, stream,
                     inp, W0, W1, W2, W3, ws);
  hipLaunchKernelGGL(liif_main, dim3(Q / 8), dim3(256), 0, stream,
                     coord, cell, b0, b1, b2, b3, ws, out);
}